// Round 15
// baseline (164.989 us; speedup 1.0000x reference)
//
#include <hip/hip_runtime.h>
#include <hip/hip_bf16.h>

typedef __bf16 bf16x8 __attribute__((ext_vector_type(8)));
typedef __bf16 bf16x4 __attribute__((ext_vector_type(4)));
typedef float  f32x4  __attribute__((ext_vector_type(4)));

#define MFMA16(a, b, c) __builtin_amdgcn_mfma_f32_16x16x32_bf16((a), (b), (c), 0, 0, 0)

typedef const __attribute__((address_space(1))) unsigned int* gas_t;
typedef __attribute__((address_space(3))) unsigned int* las_t;
// DMA global->LDS, 16B/lane, linear LDS dest (base + lane*16).
__device__ __forceinline__ void dma16(const __bf16* g, __bf16* l) {
    __builtin_amdgcn_global_load_lds((gas_t)g, (las_t)l, 16, 0, 0);
}

// Problem constants: B=8, N=1024, D=512, H=8, DH=64

// ---------------------------------------------------------------------------
// Kernel 1: fused QKV projection — ONE pass over x serves all 3 weights.
// ---------------------------------------------------------------------------
__global__ __launch_bounds__(256) void gemm_qkv(
    const float* __restrict__ x,
    const float* __restrict__ Wq, const float* __restrict__ Wk,
    const float* __restrict__ Wv,
    __bf16* __restrict__ qo, __bf16* __restrict__ ko, __bf16* __restrict__ vto)
{
    __shared__ __bf16 As[64][40];
    __shared__ __bf16 Bs[3][64][40];
    const int tid  = threadIdx.x;
    const int lane = tid & 63;
    const int wid  = tid >> 6;
    const int g    = lane >> 4, l16 = lane & 15;
    const int wr   = wid >> 1,  wc  = wid & 1;
    const int r0   = blockIdx.x * 64;
    const int c0   = blockIdx.y * 64;
    const float* Ws[3] = { Wq, Wk, Wv };

    const int sr  = tid >> 3;
    const int scq = tid & 7;

    f32x4 acc[3][2][2] = {};

    for (int k0 = 0; k0 < 512; k0 += 32) {
        __syncthreads();
#pragma unroll
        for (int j = 0; j < 2; ++j) {
            const int r = sr + 32 * j;
            float4 av = *reinterpret_cast<const float4*>(x + (size_t)(r0 + r) * 512 + k0 + scq * 4);
            bf16x4 ap = { (__bf16)av.x, (__bf16)av.y, (__bf16)av.z, (__bf16)av.w };
            *reinterpret_cast<bf16x4*>(&As[r][scq * 4]) = ap;
#pragma unroll
            for (int widx = 0; widx < 3; ++widx) {
                float4 bv = *reinterpret_cast<const float4*>(Ws[widx] + (size_t)(c0 + r) * 512 + k0 + scq * 4);
                bf16x4 bp = { (__bf16)bv.x, (__bf16)bv.y, (__bf16)bv.z, (__bf16)bv.w };
                *reinterpret_cast<bf16x4*>(&Bs[widx][r][scq * 4]) = bp;
            }
        }
        __syncthreads();
        bf16x8 af[2];
#pragma unroll
        for (int rt = 0; rt < 2; ++rt)
            af[rt] = *reinterpret_cast<const bf16x8*>(&As[wr * 32 + rt * 16 + l16][g * 8]);
#pragma unroll
        for (int widx = 0; widx < 3; ++widx) {
            bf16x8 bfr[2];
#pragma unroll
            for (int ct = 0; ct < 2; ++ct)
                bfr[ct] = *reinterpret_cast<const bf16x8*>(&Bs[widx][wc * 32 + ct * 16 + l16][g * 8]);
#pragma unroll
            for (int rt = 0; rt < 2; ++rt)
#pragma unroll
                for (int ct = 0; ct < 2; ++ct)
                    acc[widx][rt][ct] = MFMA16(af[rt], bfr[ct], acc[widx][rt][ct]);
        }
    }

#pragma unroll
    for (int widx = 0; widx < 2; ++widx) {
        __bf16* dst = (widx == 0) ? qo : ko;
        const float scale = (widx == 0) ? 0.125f : 1.0f;
#pragma unroll
        for (int rt = 0; rt < 2; ++rt)
#pragma unroll
            for (int ct = 0; ct < 2; ++ct)
#pragma unroll
                for (int reg = 0; reg < 4; ++reg) {
                    int r = r0 + wr * 32 + rt * 16 + 4 * g + reg;
                    int c = c0 + wc * 32 + ct * 16 + l16;
                    float val = acc[widx][rt][ct][reg] * scale;
                    int b = r >> 10, n = r & 1023, h = c >> 6, dh = c & 63;
                    dst[(((size_t)b * 8 + h) * 1024 + n) * 64 + dh] = (__bf16)val;
                }
    }
#pragma unroll
    for (int rt = 0; rt < 2; ++rt)
#pragma unroll
        for (int ct = 0; ct < 2; ++ct) {
            int r = r0 + wr * 32 + rt * 16 + 4 * g;
            int c = c0 + wc * 32 + ct * 16 + l16;
            int b = r >> 10, n = r & 1023, h = c >> 6, dh = c & 63;
            bf16x4 pv = { (__bf16)acc[2][rt][ct][0], (__bf16)acc[2][rt][ct][1],
                          (__bf16)acc[2][rt][ct][2], (__bf16)acc[2][rt][ct][3] };
            *reinterpret_cast<bf16x4*>(vto + (((size_t)b * 8 + h) * 64 + dh) * 1024 + n) = pv;
        }
}

// ---------------------------------------------------------------------------
// Kernel 2: fused flash attention v9 — v7 machinery at TRUE 2 blocks/CU.
// 8 waves = 8 heads (full bias-line use), Q-tile 16 rows, grid (8 b, 64 nt)
// = 512 blocks = 2/CU (LDS 62 KB, VGPR capped 128).
// - K via global_load_lds + source-XOR swizzle (wave-local, no barrier).
// - V in REGISTERS (vpA/vpB, 1-iter prefetch from L2) — no Vs LDS.
// - Bias: coalesced f32x4 nt loads, 1-deep regs (TLP covers), dbuf LDS
//   [2][8][32][20] -> b64 fragment reads.
// - Fixed-max softmax; ONE lgkm-only barrier/iter; counted vmcnt(6).
// ---------------------------------------------------------------------------
__global__ __launch_bounds__(512, 4) void attn_v9(
    const __bf16* __restrict__ qw, const __bf16* __restrict__ kw,
    const __bf16* __restrict__ vtw, const float* __restrict__ bias,
    __bf16* __restrict__ ow)
{
    __shared__ __align__(16) __bf16 Ks[8][32][64];     // 32 KB swizzled content
    __shared__ __align__(16) __bf16 bsm[2][8][32][20]; // 20 KB [buf][h][m][n]
    __shared__ __bf16 psm[8][16][40];                  // 10 KB wave-local P
    const int tid  = threadIdx.x;
    const int w    = tid >> 6;             // head
    const int lane = tid & 63;
    const int g    = lane >> 4, l16 = lane & 15;
    const int b    = blockIdx.x;
    const int n0   = blockIdx.y * 16;
    const size_t bhs = (size_t)b * 8 + w;

    const __bf16* kbase  = kw  + bhs * 1024 * 64;
    const __bf16* vbase  = vtw + bhs * 64 * 1024;
    const float*  bias_b = bias + ((size_t)(b * 1024 + n0)) * 8192;

    const int snr = tid >> 5;     // bias n-row 0..15 (32 thr/row)
    const int sf  = tid & 31;     // f32x4 chunk base (row = 64 chunks)

    const int k_row  = lane >> 3;
    const int k_csrc = (lane & 7) ^ (k_row & 7);

    bf16x8 qf[2];
#pragma unroll
    for (int kc = 0; kc < 2; ++kc)
        qf[kc] = *reinterpret_cast<const bf16x8*>(
            qw + (bhs * 1024 + n0 + l16) * 64 + kc * 32 + g * 8);

    f32x4 o[4] = {};
    float lrun[4] = {};

    f32x4  bp[2];
    bf16x8 vpA[4], vpB[4];

#define LOAD_BIAS(tt)                                                          \
    {                                                                          \
        const int m0_ = (tt) * 32;                                             \
        _Pragma("unroll")                                                      \
        for (int c = 0; c < 2; ++c)                                            \
            bp[c] = __builtin_nontemporal_load(reinterpret_cast<const f32x4*>( \
                bias_b + (size_t)snr * 8192 + m0_ * 8 + (sf + 32 * c) * 4));   \
    }

#define WRITE_BIAS(buf)                                                        \
    {                                                                          \
        _Pragma("unroll")                                                      \
        for (int c = 0; c < 2; ++c) {                                          \
            const int f4 = sf + 32 * c;                                        \
            const int mm = f4 >> 1, h0 = (f4 & 1) * 4;                         \
            bsm[buf][h0 + 0][mm][snr] = (__bf16)bp[c].x;                       \
            bsm[buf][h0 + 1][mm][snr] = (__bf16)bp[c].y;                       \
            bsm[buf][h0 + 2][mm][snr] = (__bf16)bp[c].z;                       \
            bsm[buf][h0 + 3][mm][snr] = (__bf16)bp[c].w;                       \
        }                                                                      \
    }

#define DMA_K(tt)                                                              \
    {                                                                          \
        const int m0_ = (tt) * 32;                                             \
        _Pragma("unroll")                                                      \
        for (int i = 0; i < 4; ++i)                                            \
            dma16(kbase + (size_t)(m0_ + i * 8 + k_row) * 64 + k_csrc * 8,     \
                  &Ks[w][i * 8][0]);                                           \
    }

#define LOAD_V(dst, tt)                                                        \
    {                                                                          \
        const int m0_ = (tt) * 32;                                             \
        _Pragma("unroll")                                                      \
        for (int oc = 0; oc < 4; ++oc)                                         \
            dst[oc] = *reinterpret_cast<const bf16x8*>(                        \
                vbase + (size_t)(oc * 16 + l16) * 1024 + m0_ + g * 8);         \
    }

    // ---- prologue ----
    LOAD_BIAS(0)
    DMA_K(0)
    LOAD_V(vpA, 0)
    WRITE_BIAS(0)          // compiler waits on bp's vmcnt
    LOAD_BIAS(1)
    asm volatile("s_waitcnt vmcnt(6)");   // drain K-DMA; keep bias(2)+V(4)
    __builtin_amdgcn_sched_barrier(0);
    asm volatile("s_waitcnt lgkmcnt(0)");
    __builtin_amdgcn_s_barrier();
    __builtin_amdgcn_sched_barrier(0);

#define ATTN_STEP(t, BUF, VCUR, VNXT)                                          \
    {                                                                          \
        bf16x8 kf[2][2];                                                       \
        _Pragma("unroll")                                                      \
        for (int ct = 0; ct < 2; ++ct)                                         \
            _Pragma("unroll")                                                  \
            for (int kc = 0; kc < 2; ++kc) {                                   \
                const int mrow = ct * 16 + l16;                                \
                kf[ct][kc] = *reinterpret_cast<const bf16x8*>(                 \
                    &Ks[w][mrow][(((kc * 4 + g) ^ (l16 & 7)) * 8)]);           \
            }                                                                  \
        bf16x4 bb[2];                                                          \
        _Pragma("unroll")                                                      \
        for (int ct = 0; ct < 2; ++ct)                                         \
            bb[ct] = *reinterpret_cast<const bf16x4*>(                         \
                &bsm[BUF][w][ct * 16 + l16][4 * g]);                           \
        /* K-tile reads retired -> safe to overwrite Ks[w] */                  \
        asm volatile("s_waitcnt lgkmcnt(0)");                                  \
        __builtin_amdgcn_sched_barrier(0);                                     \
        DMA_K((t) + 1 < 32 ? (t) + 1 : 31)                                     \
        LOAD_V(VNXT, (t) + 1 < 32 ? (t) + 1 : 31)                              \
        /* QK^T */                                                             \
        f32x4 s[2] = {};                                                       \
        _Pragma("unroll")                                                      \
        for (int ct = 0; ct < 2; ++ct) {                                       \
            s[ct] = MFMA16(qf[0], kf[ct][0], s[ct]);                           \
            s[ct] = MFMA16(qf[1], kf[ct][1], s[ct]);                           \
        }                                                                      \
        /* fixed-max softmax */                                                \
        _Pragma("unroll")                                                      \
        for (int reg = 0; reg < 4; ++reg) {                                    \
            const int nr = 4 * g + reg;                                        \
            float p0 = __expf(s[0][reg] + (float)bb[0][reg] - 16.0f);          \
            float p1 = __expf(s[1][reg] + (float)bb[1][reg] - 16.0f);          \
            lrun[reg] += p0 + p1;                                              \
            psm[w][nr][l16]      = (__bf16)p0;                                 \
            psm[w][nr][16 + l16] = (__bf16)p1;                                 \
        }                                                                      \
        asm volatile("s_waitcnt lgkmcnt(0)");                                  \
        __builtin_amdgcn_sched_barrier(0);                                     \
        bf16x8 pf = *reinterpret_cast<const bf16x8*>(&psm[w][l16][g * 8]);     \
        _Pragma("unroll")                                                      \
        for (int oc = 0; oc < 4; ++oc)                                         \
            o[oc] = MFMA16(pf, VCUR[oc], o[oc]);                               \
        /* stage next bias tile; refill (1-deep; TLP covers) */                \
        WRITE_BIAS((BUF) ^ 1)                                                  \
        LOAD_BIAS((t) + 2 < 32 ? (t) + 2 : 31)                                 \
        asm volatile("s_waitcnt vmcnt(6)");  /* drain K-DMA; keep bias+V */    \
        __builtin_amdgcn_sched_barrier(0);                                     \
        asm volatile("s_waitcnt lgkmcnt(0)");                                  \
        __builtin_amdgcn_s_barrier();                                          \
        __builtin_amdgcn_sched_barrier(0);                                     \
    }

    for (int t = 0; t < 32; t += 2) {
        ATTN_STEP(t,     0, vpA, vpB)
        ATTN_STEP(t + 1, 1, vpB, vpA)
    }
#undef ATTN_STEP
#undef LOAD_BIAS
#undef WRITE_BIAS
#undef DMA_K
#undef LOAD_V

    // epilogue: denominator across the 16 m-lanes
#pragma unroll
    for (int reg = 0; reg < 4; ++reg) {
        float l = lrun[reg];
        l += __shfl_xor(l, 1);
        l += __shfl_xor(l, 2);
        l += __shfl_xor(l, 4);
        l += __shfl_xor(l, 8);
        lrun[reg] = l;
    }

#pragma unroll
    for (int oc = 0; oc < 4; ++oc)
#pragma unroll
        for (int reg = 0; reg < 4; ++reg) {
            int n  = n0 + 4 * g + reg;
            int dh = oc * 16 + l16;
            float val = o[oc][reg] / lrun[reg];
            ow[((size_t)b * 1024 + n) * 512 + w * 64 + dh] = (__bf16)val;
        }
}

// ---------------------------------------------------------------------------
// Kernel 3: output projection (unchanged).
// ---------------------------------------------------------------------------
__global__ __launch_bounds__(256) void gemm_out(
    const __bf16* __restrict__ a, const float* __restrict__ Wm,
    const float* __restrict__ bm, float* __restrict__ out)
{
    __shared__ __bf16 As[64][40];
    __shared__ __bf16 Bs[64][40];
    const int tid  = threadIdx.x;
    const int lane = tid & 63;
    const int wid  = tid >> 6;
    const int g    = lane >> 4, l16 = lane & 15;
    const int wr   = wid >> 1,  wc  = wid & 1;
    const int r0   = blockIdx.x * 64;
    const int c0   = blockIdx.y * 64;

    const int sra = tid >> 2, sca = tid & 3;
    const int srb = tid >> 3, scb = tid & 7;

    f32x4 acc[2][2] = {};
    for (int k0 = 0; k0 < 512; k0 += 32) {
        __syncthreads();
        {
            bf16x8 av = *reinterpret_cast<const bf16x8*>(a + (size_t)(r0 + sra) * 512 + k0 + sca * 8);
            *reinterpret_cast<bf16x8*>(&As[sra][sca * 8]) = av;
#pragma unroll
            for (int j = 0; j < 2; ++j) {
                int r = srb + 32 * j;
                float4 bv = *reinterpret_cast<const float4*>(Wm + (size_t)(c0 + r) * 512 + k0 + scb * 4);
                bf16x4 bp = { (__bf16)bv.x, (__bf16)bv.y, (__bf16)bv.z, (__bf16)bv.w };
                *reinterpret_cast<bf16x4*>(&Bs[r][scb * 4]) = bp;
            }
        }
        __syncthreads();
        bf16x8 af[2], bfr[2];
#pragma unroll
        for (int rt = 0; rt < 2; ++rt)
            af[rt] = *reinterpret_cast<const bf16x8*>(&As[wr * 32 + rt * 16 + l16][g * 8]);
#pragma unroll
        for (int ct = 0; ct < 2; ++ct)
            bfr[ct] = *reinterpret_cast<const bf16x8*>(&Bs[wc * 32 + ct * 16 + l16][g * 8]);
#pragma unroll
        for (int rt = 0; rt < 2; ++rt)
#pragma unroll
            for (int ct = 0; ct < 2; ++ct)
                acc[rt][ct] = MFMA16(af[rt], bfr[ct], acc[rt][ct]);
    }

#pragma unroll
    for (int rt = 0; rt < 2; ++rt)
#pragma unroll
        for (int ct = 0; ct < 2; ++ct)
#pragma unroll
            for (int reg = 0; reg < 4; ++reg) {
                int r = r0 + wr * 32 + rt * 16 + 4 * g + reg;
                int c = c0 + wc * 32 + ct * 16 + l16;
                out[(size_t)r * 512 + c] = acc[rt][ct][reg] + bm[c];
            }
}

// ---------------------------------------------------------------------------
extern "C" void kernel_launch(void* const* d_in, const int* in_sizes, int n_in,
                              void* d_out, int out_size, void* d_ws, size_t ws_size,
                              hipStream_t stream)
{
    const float* x    = (const float*)d_in[0];
    const float* bias = (const float*)d_in[1];
    const float* Wq   = (const float*)d_in[2];
    const float* Wk   = (const float*)d_in[3];
    const float* Wv   = (const float*)d_in[4];
    const float* Wm   = (const float*)d_in[5];
    const float* bm   = (const float*)d_in[6];
    float* out = (float*)d_out;

    const size_t SEG = (size_t)8 * 8 * 1024 * 64;   // 4M elems (8 MB bf16) each
    __bf16* qw  = (__bf16*)d_ws;
    __bf16* kw  = qw + SEG;
    __bf16* vtw = kw + SEG;
    __bf16* ow  = vtw + SEG;

    gemm_qkv<<<dim3(128, 8), 256, 0, stream>>>(x, Wq, Wk, Wv, qw, kw, vtw);
    attn_v9 <<<dim3(8, 64), 512, 0, stream>>>(qw, kw, vtw, bias, ow);
    gemm_out<<<dim3(128, 8), 256, 0, stream>>>(ow, Wm, bm, out);
}

// Round 16
// 137.503 us; speedup vs baseline: 1.1999x; 1.1999x over previous
//
#include <hip/hip_runtime.h>
#include <hip/hip_bf16.h>

typedef __bf16 bf16x8 __attribute__((ext_vector_type(8)));
typedef __bf16 bf16x4 __attribute__((ext_vector_type(4)));
typedef float  f32x4  __attribute__((ext_vector_type(4)));

#define MFMA16(a, b, c) __builtin_amdgcn_mfma_f32_16x16x32_bf16((a), (b), (c), 0, 0, 0)

typedef const __attribute__((address_space(1))) unsigned int* gas_t;
typedef __attribute__((address_space(3))) unsigned int* las_t;
// DMA global->LDS, 16B/lane, linear LDS dest (base + lane*16).
__device__ __forceinline__ void dma16(const __bf16* g, __bf16* l) {
    __builtin_amdgcn_global_load_lds((gas_t)g, (las_t)l, 16, 0, 0);
}

// Problem constants: B=8, N=1024, D=512, H=8, DH=64

// ---------------------------------------------------------------------------
// Kernel 1: fused QKV projection — ONE pass over x serves all 3 weights.
// ---------------------------------------------------------------------------
__global__ __launch_bounds__(256) void gemm_qkv(
    const float* __restrict__ x,
    const float* __restrict__ Wq, const float* __restrict__ Wk,
    const float* __restrict__ Wv,
    __bf16* __restrict__ qo, __bf16* __restrict__ ko, __bf16* __restrict__ vto)
{
    __shared__ __bf16 As[64][40];
    __shared__ __bf16 Bs[3][64][40];
    const int tid  = threadIdx.x;
    const int lane = tid & 63;
    const int wid  = tid >> 6;
    const int g    = lane >> 4, l16 = lane & 15;
    const int wr   = wid >> 1,  wc  = wid & 1;
    const int r0   = blockIdx.x * 64;
    const int c0   = blockIdx.y * 64;
    const float* Ws[3] = { Wq, Wk, Wv };

    const int sr  = tid >> 3;
    const int scq = tid & 7;

    f32x4 acc[3][2][2] = {};

    for (int k0 = 0; k0 < 512; k0 += 32) {
        __syncthreads();
#pragma unroll
        for (int j = 0; j < 2; ++j) {
            const int r = sr + 32 * j;
            float4 av = *reinterpret_cast<const float4*>(x + (size_t)(r0 + r) * 512 + k0 + scq * 4);
            bf16x4 ap = { (__bf16)av.x, (__bf16)av.y, (__bf16)av.z, (__bf16)av.w };
            *reinterpret_cast<bf16x4*>(&As[r][scq * 4]) = ap;
#pragma unroll
            for (int widx = 0; widx < 3; ++widx) {
                float4 bv = *reinterpret_cast<const float4*>(Ws[widx] + (size_t)(c0 + r) * 512 + k0 + scq * 4);
                bf16x4 bp = { (__bf16)bv.x, (__bf16)bv.y, (__bf16)bv.z, (__bf16)bv.w };
                *reinterpret_cast<bf16x4*>(&Bs[widx][r][scq * 4]) = bp;
            }
        }
        __syncthreads();
        bf16x8 af[2];
#pragma unroll
        for (int rt = 0; rt < 2; ++rt)
            af[rt] = *reinterpret_cast<const bf16x8*>(&As[wr * 32 + rt * 16 + l16][g * 8]);
#pragma unroll
        for (int widx = 0; widx < 3; ++widx) {
            bf16x8 bfr[2];
#pragma unroll
            for (int ct = 0; ct < 2; ++ct)
                bfr[ct] = *reinterpret_cast<const bf16x8*>(&Bs[widx][wc * 32 + ct * 16 + l16][g * 8]);
#pragma unroll
            for (int rt = 0; rt < 2; ++rt)
#pragma unroll
                for (int ct = 0; ct < 2; ++ct)
                    acc[widx][rt][ct] = MFMA16(af[rt], bfr[ct], acc[widx][rt][ct]);
        }
    }

#pragma unroll
    for (int widx = 0; widx < 2; ++widx) {
        __bf16* dst = (widx == 0) ? qo : ko;
        const float scale = (widx == 0) ? 0.125f : 1.0f;
#pragma unroll
        for (int rt = 0; rt < 2; ++rt)
#pragma unroll
            for (int ct = 0; ct < 2; ++ct)
#pragma unroll
                for (int reg = 0; reg < 4; ++reg) {
                    int r = r0 + wr * 32 + rt * 16 + 4 * g + reg;
                    int c = c0 + wc * 32 + ct * 16 + l16;
                    float val = acc[widx][rt][ct][reg] * scale;
                    int b = r >> 10, n = r & 1023, h = c >> 6, dh = c & 63;
                    dst[(((size_t)b * 8 + h) * 1024 + n) * 64 + dh] = (__bf16)val;
                }
    }
#pragma unroll
    for (int rt = 0; rt < 2; ++rt)
#pragma unroll
        for (int ct = 0; ct < 2; ++ct) {
            int r = r0 + wr * 32 + rt * 16 + 4 * g;
            int c = c0 + wc * 32 + ct * 16 + l16;
            int b = r >> 10, n = r & 1023, h = c >> 6, dh = c & 63;
            bf16x4 pv = { (__bf16)acc[2][rt][ct][0], (__bf16)acc[2][rt][ct][1],
                          (__bf16)acc[2][rt][ct][2], (__bf16)acc[2][rt][ct][3] };
            *reinterpret_cast<bf16x4*>(vto + (((size_t)b * 8 + h) * 64 + dh) * 1024 + n) = pv;
        }
}

// ---------------------------------------------------------------------------
// Kernel 2: fused flash attention v10 = v7 machinery at BK=64.
// 8 waves = 8 heads, 32 Q-rows, grid (8 b, 32 nt), 1 block/CU, 16 rounds.
// - K via global_load_lds + source-XOR swizzle, Ks[8][64][64] single-buf.
// - Bias: 2KB/row contiguous nt f32x4 bursts, 1-deep reg pipeline (full
//   round of cover), single-buffered LDS [h][m][n] (plane stride 2178).
// - V to registers same-iter from L2 (no LDS, no ping-pong).
// - Fixed-max softmax; 2 lgkm-only barriers/round; counted vmcnt(8).
// ---------------------------------------------------------------------------
__global__ __launch_bounds__(512) void attn_v10(
    const __bf16* __restrict__ qw, const __bf16* __restrict__ kw,
    const __bf16* __restrict__ vtw, const float* __restrict__ bias,
    __bf16* __restrict__ ow)
{
    __shared__ __align__(16) __bf16 Ks[8][64][64];   // 64 KB swizzled content
    __shared__ __align__(16) __bf16 bsm[8 * 2178];   // 34.8 KB [h][m64][n34]
    __shared__ __align__(16) __bf16 psm[8 * 2178];   // 34.8 KB [w][n32][m68]
    const int tid  = threadIdx.x;
    const int w    = tid >> 6;             // head
    const int lane = tid & 63;
    const int g    = lane >> 4, l16 = lane & 15;
    const int b    = blockIdx.x;
    const int n0   = blockIdx.y * 32;
    const size_t bhs = (size_t)b * 8 + w;

    const __bf16* kbase  = kw  + bhs * 1024 * 64;
    const __bf16* vbase  = vtw + bhs * 64 * 1024;
    const float*  bias_b = bias + ((size_t)(b * 1024 + n0)) * 8192;

    const int snr = tid >> 4;     // bias n-row 0..31 (16 thr/row)
    const int sf  = tid & 15;     // f32x4 chunk base (row tile = 128 chunks)

    const int k_row  = lane >> 3;
    const int k_csrc = (lane & 7) ^ (k_row & 7);

    bf16x8 qf[2][2];
#pragma unroll
    for (int rf = 0; rf < 2; ++rf)
#pragma unroll
        for (int kc = 0; kc < 2; ++kc)
            qf[rf][kc] = *reinterpret_cast<const bf16x8*>(
                qw + (bhs * 1024 + n0 + rf * 16 + l16) * 64 + kc * 32 + g * 8);

    f32x4 o[2][4] = {};
    float lrun[2][4] = {};

    f32x4 bp[8];   // one bias round (32n x 64m x 8h) / 512 thr = 8 f32x4

#define LOAD_BIAS(tt)                                                          \
    {                                                                          \
        const int m0_ = (tt) * 64;                                             \
        _Pragma("unroll")                                                      \
        for (int c = 0; c < 8; ++c)                                            \
            bp[c] = __builtin_nontemporal_load(reinterpret_cast<const f32x4*>( \
                bias_b + (size_t)snr * 8192 + m0_ * 8 + (sf + 16 * c) * 4));   \
    }

#define WRITE_BIAS()                                                           \
    {                                                                          \
        _Pragma("unroll")                                                      \
        for (int c = 0; c < 8; ++c) {                                          \
            const int f4 = sf + 16 * c;                                        \
            const int mm = f4 >> 1, h0 = (f4 & 1) * 4;                         \
            bsm[(h0 + 0) * 2178 + mm * 34 + snr] = (__bf16)bp[c].x;            \
            bsm[(h0 + 1) * 2178 + mm * 34 + snr] = (__bf16)bp[c].y;            \
            bsm[(h0 + 2) * 2178 + mm * 34 + snr] = (__bf16)bp[c].z;            \
            bsm[(h0 + 3) * 2178 + mm * 34 + snr] = (__bf16)bp[c].w;            \
        }                                                                      \
    }

#define DMA_K(tt)                                                              \
    {                                                                          \
        const int m0_ = (tt) * 64;                                             \
        _Pragma("unroll")                                                      \
        for (int i = 0; i < 8; ++i)                                            \
            dma16(kbase + (size_t)(m0_ + i * 8 + k_row) * 64 + k_csrc * 8,     \
                  &Ks[w][i * 8][0]);                                           \
    }

    // ---- prologue: round 0 ----
    LOAD_BIAS(0)
    DMA_K(0)
    WRITE_BIAS()              // compiler waits bp's vmcnt
    LOAD_BIAS(1)
    asm volatile("s_waitcnt vmcnt(8)");   // drain K-DMA; keep bias(8)
    __builtin_amdgcn_sched_barrier(0);
    asm volatile("s_waitcnt lgkmcnt(0)");
    __builtin_amdgcn_s_barrier();
    __builtin_amdgcn_sched_barrier(0);

    for (int t = 0; t < 16; ++t) {
        // --- fragment reads for round t (K swizzled b128, bias b64) ---
        bf16x8 kf[4][2];
#pragma unroll
        for (int ct = 0; ct < 4; ++ct)
#pragma unroll
            for (int kc = 0; kc < 2; ++kc) {
                const int mrow = ct * 16 + l16;
                kf[ct][kc] = *reinterpret_cast<const bf16x8*>(
                    &Ks[w][mrow][(((kc * 4 + g) ^ (l16 & 7)) * 8)]);
            }
        bf16x4 bb[2][4];
#pragma unroll
        for (int rf = 0; rf < 2; ++rf)
#pragma unroll
            for (int ct = 0; ct < 4; ++ct)
                bb[rf][ct] = *reinterpret_cast<const bf16x4*>(
                    &bsm[w * 2178 + (ct * 16 + l16) * 34 + rf * 16 + 4 * g]);
        asm volatile("s_waitcnt lgkmcnt(0)");
        __builtin_amdgcn_sched_barrier(0);

        // issue next round's K-DMA (Ks wave-local, reads already in regs)
        const int tn = (t + 1 < 16) ? t + 1 : 15;
        DMA_K(tn)

        // V for this round, straight from L2 to regs
        bf16x8 vp[8];
        {
            const int m0_ = t * 64;
#pragma unroll
            for (int oc = 0; oc < 4; ++oc)
#pragma unroll
                for (int mc = 0; mc < 2; ++mc)
                    vp[oc * 2 + mc] = *reinterpret_cast<const bf16x8*>(
                        vbase + (size_t)(oc * 16 + l16) * 1024 + m0_ + mc * 32 + g * 8);
        }

        __builtin_amdgcn_s_barrier();        // all waves done reading bsm
        __builtin_amdgcn_sched_barrier(0);

        // stage bias round t+1 from regs; refill regs with round t+2
        WRITE_BIAS()
        LOAD_BIAS((t + 2 < 16) ? t + 2 : 15)

        // QK^T (K=64 via 2 kc chunks, 4 ct tiles)
        f32x4 s[2][4] = {};
#pragma unroll
        for (int rf = 0; rf < 2; ++rf)
#pragma unroll
            for (int ct = 0; ct < 4; ++ct) {
                s[rf][ct] = MFMA16(qf[rf][0], kf[ct][0], s[rf][ct]);
                s[rf][ct] = MFMA16(qf[rf][1], kf[ct][1], s[rf][ct]);
            }

        // fixed-max softmax -> psm
#pragma unroll
        for (int rf = 0; rf < 2; ++rf)
#pragma unroll
            for (int ct = 0; ct < 4; ++ct)
#pragma unroll
                for (int reg = 0; reg < 4; ++reg) {
                    const int nr = rf * 16 + 4 * g + reg;
                    float p = __expf(s[rf][ct][reg] + (float)bb[rf][ct][reg] - 16.0f);
                    lrun[rf][reg] += p;
                    psm[w * 2178 + nr * 68 + ct * 16 + l16] = (__bf16)p;
                }
        asm volatile("s_waitcnt lgkmcnt(0)");
        __builtin_amdgcn_sched_barrier(0);

        // P relayout + PV (2 m-chunks)
        bf16x8 pf[2][2];
#pragma unroll
        for (int rf = 0; rf < 2; ++rf)
#pragma unroll
            for (int mc = 0; mc < 2; ++mc)
                pf[rf][mc] = *reinterpret_cast<const bf16x8*>(
                    &psm[w * 2178 + (rf * 16 + l16) * 68 + mc * 32 + g * 8]);
#pragma unroll
        for (int rf = 0; rf < 2; ++rf)
#pragma unroll
            for (int oc = 0; oc < 4; ++oc) {
                o[rf][oc] = MFMA16(pf[rf][0], vp[oc * 2 + 0], o[rf][oc]);
                o[rf][oc] = MFMA16(pf[rf][1], vp[oc * 2 + 1], o[rf][oc]);
            }

        // drain this round's K-DMA (keep the 8 newest bias loads in flight)
        asm volatile("s_waitcnt vmcnt(8)");
        __builtin_amdgcn_sched_barrier(0);
        asm volatile("s_waitcnt lgkmcnt(0)");
        __builtin_amdgcn_s_barrier();        // bsm round t+1 visible
        __builtin_amdgcn_sched_barrier(0);
    }
#undef LOAD_BIAS
#undef WRITE_BIAS
#undef DMA_K

    // epilogue: denominator across the 16 m-lanes
#pragma unroll
    for (int rf = 0; rf < 2; ++rf)
#pragma unroll
        for (int reg = 0; reg < 4; ++reg) {
            float l = lrun[rf][reg];
            l += __shfl_xor(l, 1);
            l += __shfl_xor(l, 2);
            l += __shfl_xor(l, 4);
            l += __shfl_xor(l, 8);
            lrun[rf][reg] = l;
        }

#pragma unroll
    for (int rf = 0; rf < 2; ++rf)
#pragma unroll
        for (int oc = 0; oc < 4; ++oc)
#pragma unroll
            for (int reg = 0; reg < 4; ++reg) {
                int n  = n0 + rf * 16 + 4 * g + reg;
                int dh = oc * 16 + l16;
                float val = o[rf][oc][reg] / lrun[rf][reg];
                ow[((size_t)b * 1024 + n) * 512 + w * 64 + dh] = (__bf16)val;
            }
}

// ---------------------------------------------------------------------------
// Kernel 3: output projection (unchanged).
// ---------------------------------------------------------------------------
__global__ __launch_bounds__(256) void gemm_out(
    const __bf16* __restrict__ a, const float* __restrict__ Wm,
    const float* __restrict__ bm, float* __restrict__ out)
{
    __shared__ __bf16 As[64][40];
    __shared__ __bf16 Bs[64][40];
    const int tid  = threadIdx.x;
    const int lane = tid & 63;
    const int wid  = tid >> 6;
    const int g    = lane >> 4, l16 = lane & 15;
    const int wr   = wid >> 1,  wc  = wid & 1;
    const int r0   = blockIdx.x * 64;
    const int c0   = blockIdx.y * 64;

    const int sra = tid >> 2, sca = tid & 3;
    const int srb = tid >> 3, scb = tid & 7;

    f32x4 acc[2][2] = {};
    for (int k0 = 0; k0 < 512; k0 += 32) {
        __syncthreads();
        {
            bf16x8 av = *reinterpret_cast<const bf16x8*>(a + (size_t)(r0 + sra) * 512 + k0 + sca * 8);
            *reinterpret_cast<bf16x8*>(&As[sra][sca * 8]) = av;
#pragma unroll
            for (int j = 0; j < 2; ++j) {
                int r = srb + 32 * j;
                float4 bv = *reinterpret_cast<const float4*>(Wm + (size_t)(c0 + r) * 512 + k0 + scb * 4);
                bf16x4 bp = { (__bf16)bv.x, (__bf16)bv.y, (__bf16)bv.z, (__bf16)bv.w };
                *reinterpret_cast<bf16x4*>(&Bs[r][scb * 4]) = bp;
            }
        }
        __syncthreads();
        bf16x8 af[2], bfr[2];
#pragma unroll
        for (int rt = 0; rt < 2; ++rt)
            af[rt] = *reinterpret_cast<const bf16x8*>(&As[wr * 32 + rt * 16 + l16][g * 8]);
#pragma unroll
        for (int ct = 0; ct < 2; ++ct)
            bfr[ct] = *reinterpret_cast<const bf16x8*>(&Bs[wc * 32 + ct * 16 + l16][g * 8]);
#pragma unroll
        for (int rt = 0; rt < 2; ++rt)
#pragma unroll
            for (int ct = 0; ct < 2; ++ct)
                acc[rt][ct] = MFMA16(af[rt], bfr[ct], acc[rt][ct]);
    }

#pragma unroll
    for (int rt = 0; rt < 2; ++rt)
#pragma unroll
        for (int ct = 0; ct < 2; ++ct)
#pragma unroll
            for (int reg = 0; reg < 4; ++reg) {
                int r = r0 + wr * 32 + rt * 16 + 4 * g + reg;
                int c = c0 + wc * 32 + ct * 16 + l16;
                out[(size_t)r * 512 + c] = acc[rt][ct][reg] + bm[c];
            }
}

// ---------------------------------------------------------------------------
extern "C" void kernel_launch(void* const* d_in, const int* in_sizes, int n_in,
                              void* d_out, int out_size, void* d_ws, size_t ws_size,
                              hipStream_t stream)
{
    const float* x    = (const float*)d_in[0];
    const float* bias = (const float*)d_in[1];
    const float* Wq   = (const float*)d_in[2];
    const float* Wk   = (const float*)d_in[3];
    const float* Wv   = (const float*)d_in[4];
    const float* Wm   = (const float*)d_in[5];
    const float* bm   = (const float*)d_in[6];
    float* out = (float*)d_out;

    const size_t SEG = (size_t)8 * 8 * 1024 * 64;   // 4M elems (8 MB bf16) each
    __bf16* qw  = (__bf16*)d_ws;
    __bf16* kw  = qw + SEG;
    __bf16* vtw = kw + SEG;
    __bf16* ow  = vtw + SEG;

    gemm_qkv<<<dim3(128, 8), 256, 0, stream>>>(x, Wq, Wk, Wv, qw, kw, vtw);
    attn_v10<<<dim3(8, 32), 512, 0, stream>>>(qw, kw, vtw, bias, ow);
    gemm_out<<<dim3(128, 8), 256, 0, stream>>>(ow, Wm, bm, out);
}